// Round 9
// baseline (222.569 us; speedup 1.0000x reference)
//
#include <hip/hip_runtime.h>
#include <math.h>

#define N 4096
#define B 2048
#define RANK 4
#define ALPHA 0.8862269254527580f   // sqrt(pi)/2
#define INV_N (1.0f / 4096.0f)

#define RPB1 8                      // rows per block, kernel 1
#define NBLK1 (N / RPB1)            // 512 blocks
#define ACCSZ (5 * B)               // acc plane: s[4][B] + zdot[B] = 10240
#define RPB3 4                      // rows per block, kernel 3

// __builtin_nontemporal_* requires ext_vector_type, not HIP_vector_type
typedef float vf4 __attribute__((ext_vector_type(4)));

// Branchless Winitzki erf (max abs err ~2.5e-4; thresholds are 0.24).
__device__ __forceinline__ float erf_fast(float t) {
  const float A = 0.140012288f;
  const float FP = 1.2732395447f;  // 4/pi
  float t2 = t * t;
  float num = fmaf(A, t2, FP);
  float den = fmaf(A, t2, 1.0f);
  float r = t2 * num * __builtin_amdgcn_rcpf(den);
  float e = __expf(-r);
  float s = __builtin_amdgcn_sqrtf(fmaxf(1.0f - e, 0.0f));
  return copysignf(s, t);
}

// ---------------------------------------------------------------------------
// Kernel 0: zero the 40 KB accumulator (harness poisons ws with 0xAA).
// ---------------------------------------------------------------------------
__global__ __launch_bounds__(512) void k_zero(float* __restrict__ acc) {
  acc[blockIdx.x * 512 + threadIdx.x] = 0.f;
}

// ---------------------------------------------------------------------------
// Kernel 1: rank-4 (+z) reduction, direct atomic accumulation.
// 512 blocks x 512 thr (2 blocks/CU, 16 waves/CU). Block owns 8 whole rows =
// 64 KB contiguous slab of h; thread t owns cols 4t..4t+3; 8 unrolled vf4
// loads; v/z via block-uniform (hoisted s_load) indices. Finishes with 20
// unsafeAtomicAdd (native global_atomic_add_f32, L2-side) into acc[5][B]:
// replaces the 21 MB partials write + 21 MB k2 re-read + the whole k2 node.
// Per-address chain depth 512 (~1-2 us tail); order nondeterminism is fine
// (fp32, threshold 0.24 vs current 0.03).
// ---------------------------------------------------------------------------
__global__ __launch_bounds__(512) void k_reduce_partial(
    const float* __restrict__ h, const float* __restrict__ v,
    const float* __restrict__ z, float* __restrict__ acc) {
  const int tid = threadIdx.x;
  const int row0 = blockIdx.x * RPB1;

  vf4 a0 = {0.f, 0.f, 0.f, 0.f};
  vf4 a1 = a0, a2 = a0, a3 = a0, a4 = a0;

  const float* hp = h + (size_t)row0 * B + tid * 4;
#pragma unroll
  for (int r = 0; r < RPB1; ++r) {
    const vf4 hv = *(const vf4*)(hp + (size_t)r * B);
    vf4 p;
    p.x = erf_fast(ALPHA * hv.x);
    p.y = erf_fast(ALPHA * hv.y);
    p.z = erf_fast(ALPHA * hv.z);
    p.w = erf_fast(ALPHA * hv.w);
    const float v0 = v[(row0 + r) * RANK + 0];
    const float v1 = v[(row0 + r) * RANK + 1];
    const float v2 = v[(row0 + r) * RANK + 2];
    const float v3 = v[(row0 + r) * RANK + 3];
    const float zr = z[row0 + r];
    a0.x = fmaf(v0, p.x, a0.x); a0.y = fmaf(v0, p.y, a0.y);
    a0.z = fmaf(v0, p.z, a0.z); a0.w = fmaf(v0, p.w, a0.w);
    a1.x = fmaf(v1, p.x, a1.x); a1.y = fmaf(v1, p.y, a1.y);
    a1.z = fmaf(v1, p.z, a1.z); a1.w = fmaf(v1, p.w, a1.w);
    a2.x = fmaf(v2, p.x, a2.x); a2.y = fmaf(v2, p.y, a2.y);
    a2.z = fmaf(v2, p.z, a2.z); a2.w = fmaf(v2, p.w, a2.w);
    a3.x = fmaf(v3, p.x, a3.x); a3.y = fmaf(v3, p.y, a3.y);
    a3.z = fmaf(v3, p.z, a3.z); a3.w = fmaf(v3, p.w, a3.w);
    a4.x = fmaf(zr, p.x, a4.x); a4.y = fmaf(zr, p.y, a4.y);
    a4.z = fmaf(zr, p.z, a4.z); a4.w = fmaf(zr, p.w, a4.w);
  }

  const int c0 = tid * 4;
  unsafeAtomicAdd(acc + 0 * B + c0 + 0, a0.x);
  unsafeAtomicAdd(acc + 0 * B + c0 + 1, a0.y);
  unsafeAtomicAdd(acc + 0 * B + c0 + 2, a0.z);
  unsafeAtomicAdd(acc + 0 * B + c0 + 3, a0.w);
  unsafeAtomicAdd(acc + 1 * B + c0 + 0, a1.x);
  unsafeAtomicAdd(acc + 1 * B + c0 + 1, a1.y);
  unsafeAtomicAdd(acc + 1 * B + c0 + 2, a1.z);
  unsafeAtomicAdd(acc + 1 * B + c0 + 3, a1.w);
  unsafeAtomicAdd(acc + 2 * B + c0 + 0, a2.x);
  unsafeAtomicAdd(acc + 2 * B + c0 + 1, a2.y);
  unsafeAtomicAdd(acc + 2 * B + c0 + 2, a2.z);
  unsafeAtomicAdd(acc + 2 * B + c0 + 3, a2.w);
  unsafeAtomicAdd(acc + 3 * B + c0 + 0, a3.x);
  unsafeAtomicAdd(acc + 3 * B + c0 + 1, a3.y);
  unsafeAtomicAdd(acc + 3 * B + c0 + 2, a3.z);
  unsafeAtomicAdd(acc + 3 * B + c0 + 3, a3.w);
  unsafeAtomicAdd(acc + 4 * B + c0 + 0, a4.x);
  unsafeAtomicAdd(acc + 4 * B + c0 + 1, a4.y);
  unsafeAtomicAdd(acc + 4 * B + c0 + 2, a4.z);
  unsafeAtomicAdd(acc + 4 * B + c0 + 3, a4.w);
}

// ---------------------------------------------------------------------------
// Kernel 3: h_new[n][b] = (sum_r u[n][r]*acc[r][b])/N + m[n]*x[b]
// (DT/TAU = 1 -> h cancels exactly; h is never read.)
// 1024 blocks x 256 thr; block owns 4 whole rows = 32 KB contiguous
// nontemporal store slab. Block 0 additionally writes y = acc[4]*INV_N.
// ---------------------------------------------------------------------------
__global__ __launch_bounds__(256) void k_update(
    const float* __restrict__ acc, const float* __restrict__ u,
    const float* __restrict__ m, const float* __restrict__ x,
    float* __restrict__ hnew, float* __restrict__ y) {
  const int tid = threadIdx.x;
  const int row0 = blockIdx.x * RPB3;
  const int c0 = tid * 4;

  if (blockIdx.x == 0) {  // y = (z.T @ phi) / N from plane 4
    const vf4 t0 = *(const vf4*)(acc + 4 * B + c0);
    const vf4 t1 = *(const vf4*)(acc + 4 * B + c0 + 1024);
    *(vf4*)(y + c0) = t0 * INV_N;
    *(vf4*)(y + c0 + 1024) = t1 * INV_N;
  }

  const vf4 sA0 = *(const vf4*)(acc + 0 * B + c0);
  const vf4 sA1 = *(const vf4*)(acc + 1 * B + c0);
  const vf4 sA2 = *(const vf4*)(acc + 2 * B + c0);
  const vf4 sA3 = *(const vf4*)(acc + 3 * B + c0);
  const vf4 xa  = *(const vf4*)(x + c0);
  const vf4 sB0 = *(const vf4*)(acc + 0 * B + c0 + 1024);
  const vf4 sB1 = *(const vf4*)(acc + 1 * B + c0 + 1024);
  const vf4 sB2 = *(const vf4*)(acc + 2 * B + c0 + 1024);
  const vf4 sB3 = *(const vf4*)(acc + 3 * B + c0 + 1024);
  const vf4 xb  = *(const vf4*)(x + c0 + 1024);

  float* op = hnew + (size_t)row0 * B + c0;
#pragma unroll
  for (int i = 0; i < RPB3; ++i) {
    const int n = row0 + i;
    const vf4 uv = *(const vf4*)(u + (size_t)n * RANK);
    const float mv = m[n];
    vf4 oA, oB;
    oA.x = fmaf(mv, xa.x,
                (sA0.x * uv.x + sA1.x * uv.y + sA2.x * uv.z + sA3.x * uv.w) * INV_N);
    oA.y = fmaf(mv, xa.y,
                (sA0.y * uv.x + sA1.y * uv.y + sA2.y * uv.z + sA3.y * uv.w) * INV_N);
    oA.z = fmaf(mv, xa.z,
                (sA0.z * uv.x + sA1.z * uv.y + sA2.z * uv.z + sA3.z * uv.w) * INV_N);
    oA.w = fmaf(mv, xa.w,
                (sA0.w * uv.x + sA1.w * uv.y + sA2.w * uv.z + sA3.w * uv.w) * INV_N);
    oB.x = fmaf(mv, xb.x,
                (sB0.x * uv.x + sB1.x * uv.y + sB2.x * uv.z + sB3.x * uv.w) * INV_N);
    oB.y = fmaf(mv, xb.y,
                (sB0.y * uv.x + sB1.y * uv.y + sB2.y * uv.z + sB3.y * uv.w) * INV_N);
    oB.z = fmaf(mv, xb.z,
                (sB0.z * uv.x + sB1.z * uv.y + sB2.z * uv.z + sB3.z * uv.w) * INV_N);
    oB.w = fmaf(mv, xb.w,
                (sB0.w * uv.x + sB1.w * uv.y + sB2.w * uv.z + sB3.w * uv.w) * INV_N);
    __builtin_nontemporal_store(oA, (vf4*)(op + (size_t)i * B));
    __builtin_nontemporal_store(oB, (vf4*)(op + (size_t)i * B + 1024));
  }
}

// ---------------------------------------------------------------------------
extern "C" void kernel_launch(void* const* d_in, const int* in_sizes, int n_in,
                              void* d_out, int out_size, void* d_ws,
                              size_t ws_size, hipStream_t stream) {
  const float* x = (const float*)d_in[0];  // [1, B]
  const float* h = (const float*)d_in[1];  // [N, B]
  const float* m = (const float*)d_in[2];  // [N, 1]
  const float* u = (const float*)d_in[3];  // [N, RANK]
  const float* v = (const float*)d_in[4];  // [N, RANK]
  const float* z = (const float*)d_in[5];  // [N, 1]

  float* y = (float*)d_out;            // output 0: y [1, B]
  float* hnew = (float*)d_out + B;     // output 1: h_new [N, B]

  float* acc = (float*)d_ws;           // [5][B] = 40 KB accumulator

  k_zero<<<ACCSZ / 512, 512, 0, stream>>>(acc);
  k_reduce_partial<<<NBLK1, 512, 0, stream>>>(h, v, z, acc);
  k_update<<<N / RPB3, 256, 0, stream>>>(acc, u, m, x, hnew, y);
}

// Round 11
// 104.005 us; speedup vs baseline: 2.1400x; 2.1400x over previous
//
#include <hip/hip_runtime.h>
#include <math.h>

#define N 4096
#define B 2048
#define RANK 4
#define ALPHA 0.8862269254527580f   // sqrt(pi)/2
#define INV_N (1.0f / 4096.0f)

#define RPB1 8                      // rows per block, kernel 1
#define SPLITS (N / RPB1)           // 512 partial splits
#define P (5 * B)                   // one partial plane = 10240 elements
#define STRIPE 64                   // kernel-2 column stripe
#define GRP 8                       // split-groups per stripe
#define SPG (SPLITS / GRP)          // 64 splits per group
#define RPB3 4                      // rows per block, kernel 3

// __builtin_nontemporal_* requires ext_vector_type, not HIP_vector_type
typedef float vf4 __attribute__((ext_vector_type(4)));
typedef unsigned short vus4 __attribute__((ext_vector_type(4)));

// Branchless Winitzki erf (max abs err ~2.5e-4; thresholds are 0.24).
__device__ __forceinline__ float erf_fast(float t) {
  const float A = 0.140012288f;
  const float FP = 1.2732395447f;  // 4/pi
  float t2 = t * t;
  float num = fmaf(A, t2, FP);
  float den = fmaf(A, t2, 1.0f);
  float r = t2 * num * __builtin_amdgcn_rcpf(den);
  float e = __expf(-r);
  float s = __builtin_amdgcn_sqrtf(fmaxf(1.0f - e, 0.0f));
  return copysignf(s, t);
}

// Manual bf16 pack/unpack (this ROCm's __hip_bfloat16 lacks .data).
// RNE round-to-nearest-even; values here are finite & well-scaled (no
// NaN/Inf path needed).
__device__ __forceinline__ unsigned short f2bf(float f) {
  unsigned int u = __builtin_bit_cast(unsigned int, f);
  u += 0x7FFFu + ((u >> 16) & 1u);
  return (unsigned short)(u >> 16);
}
__device__ __forceinline__ float bf2f(unsigned short s) {
  unsigned int u = ((unsigned int)s) << 16;
  return __builtin_bit_cast(float, u);
}

// ---------------------------------------------------------------------------
// Kernel 1: rank-4 (+z) partial reduction (R8 structure, bf16 partials).
// 512 blocks x 512 thr (2 blocks/CU, 16 waves/CU). Block owns 8 whole rows =
// 64 KB contiguous slab of h; thread t owns cols 4t..4t+3; 8 unrolled vf4
// loads; v/z via block-uniform (hoisted s_load) indices.
// Partials stored bf16: halves the 21 MB round-trip (bf16 err ~5e-3/partial,
// random-walk ~0.1 on s -> ~5e-5 in h_new; threshold 0.24).
// ---------------------------------------------------------------------------
__global__ __launch_bounds__(512) void k_reduce_partial(
    const float* __restrict__ h, const float* __restrict__ v,
    const float* __restrict__ z, unsigned short* __restrict__ partials) {
  const int tid = threadIdx.x;
  const int row0 = blockIdx.x * RPB1;

  vf4 a0 = {0.f, 0.f, 0.f, 0.f};
  vf4 a1 = a0, a2 = a0, a3 = a0, a4 = a0;

  const float* hp = h + (size_t)row0 * B + tid * 4;
#pragma unroll
  for (int r = 0; r < RPB1; ++r) {
    const vf4 hv = *(const vf4*)(hp + (size_t)r * B);
    vf4 p;
    p.x = erf_fast(ALPHA * hv.x);
    p.y = erf_fast(ALPHA * hv.y);
    p.z = erf_fast(ALPHA * hv.z);
    p.w = erf_fast(ALPHA * hv.w);
    const float v0 = v[(row0 + r) * RANK + 0];
    const float v1 = v[(row0 + r) * RANK + 1];
    const float v2 = v[(row0 + r) * RANK + 2];
    const float v3 = v[(row0 + r) * RANK + 3];
    const float zr = z[row0 + r];
    a0.x = fmaf(v0, p.x, a0.x); a0.y = fmaf(v0, p.y, a0.y);
    a0.z = fmaf(v0, p.z, a0.z); a0.w = fmaf(v0, p.w, a0.w);
    a1.x = fmaf(v1, p.x, a1.x); a1.y = fmaf(v1, p.y, a1.y);
    a1.z = fmaf(v1, p.z, a1.z); a1.w = fmaf(v1, p.w, a1.w);
    a2.x = fmaf(v2, p.x, a2.x); a2.y = fmaf(v2, p.y, a2.y);
    a2.z = fmaf(v2, p.z, a2.z); a2.w = fmaf(v2, p.w, a2.w);
    a3.x = fmaf(v3, p.x, a3.x); a3.y = fmaf(v3, p.y, a3.y);
    a3.z = fmaf(v3, p.z, a3.z); a3.w = fmaf(v3, p.w, a3.w);
    a4.x = fmaf(zr, p.x, a4.x); a4.y = fmaf(zr, p.y, a4.y);
    a4.z = fmaf(zr, p.z, a4.z); a4.w = fmaf(zr, p.w, a4.w);
  }

  unsigned short* pp = partials + (size_t)blockIdx.x * P + tid * 4;
  vus4 w0 = {f2bf(a0.x), f2bf(a0.y), f2bf(a0.z), f2bf(a0.w)};
  vus4 w1 = {f2bf(a1.x), f2bf(a1.y), f2bf(a1.z), f2bf(a1.w)};
  vus4 w2 = {f2bf(a2.x), f2bf(a2.y), f2bf(a2.z), f2bf(a2.w)};
  vus4 w3 = {f2bf(a3.x), f2bf(a3.y), f2bf(a3.z), f2bf(a3.w)};
  vus4 w4 = {f2bf(a4.x), f2bf(a4.y), f2bf(a4.z), f2bf(a4.w)};
  *(vus4*)(pp + 0 * B) = w0;
  *(vus4*)(pp + 1 * B) = w1;
  *(vus4*)(pp + 2 * B) = w2;
  *(vus4*)(pp + 3 * B) = w3;
  *(vus4*)(pp + 4 * B) = w4;
}

// ---------------------------------------------------------------------------
// Kernel 2: 512 bf16 splits -> sfin[4][B] (fp32) + y[B], one kernel.
// 160 blocks x 512 thr; block owns a 64-col stripe of the [5][B] plane.
// Wave-group g (tid>>6) sums SPG=64 splits (128 B coalesced per iter,
// unroll-8 independent loads), LDS tree [8][64], 64 threads write stripe.
// ---------------------------------------------------------------------------
__global__ __launch_bounds__(512) void k_reduce_final(
    const unsigned short* __restrict__ partials, float* __restrict__ sfin,
    float* __restrict__ y) {
  __shared__ float red[GRP][STRIPE];
  const int c = threadIdx.x & (STRIPE - 1);
  const int g = threadIdx.x >> 6;  // wave-uniform, 0..7
  const int f0 = blockIdx.x * STRIPE;
  const unsigned short* pp = partials + (size_t)(g * SPG) * P + f0 + c;
  float ssum = 0.f;
#pragma unroll 8
  for (int sp = 0; sp < SPG; ++sp)
    ssum += bf2f(pp[(size_t)sp * P]);
  red[g][c] = ssum;
  __syncthreads();
  if (threadIdx.x < STRIPE) {
    float tot = 0.f;
#pragma unroll
    for (int g2 = 0; g2 < GRP; ++g2)
      tot += red[g2][threadIdx.x];
    const int f = f0 + threadIdx.x;
    if (f < RANK * B)
      sfin[f] = tot;
    else
      y[f - RANK * B] = tot * INV_N;  // y = (z.T @ phi) / N
  }
}

// ---------------------------------------------------------------------------
// Kernel 3: h_new[n][b] = (sum_r u[n][r]*sfin[r][b])/N + m[n]*x[b]
// (DT/TAU = 1 -> h cancels exactly; h is never read.)
// 1024 blocks x 256 thr; block owns 4 whole rows = 32 KB contiguous
// nontemporal store slab. Thread t owns cols 4t and 4t+1024.
// ---------------------------------------------------------------------------
__global__ __launch_bounds__(256) void k_update(
    const float* __restrict__ sfin, const float* __restrict__ u,
    const float* __restrict__ m, const float* __restrict__ x,
    float* __restrict__ hnew) {
  const int tid = threadIdx.x;
  const int row0 = blockIdx.x * RPB3;
  const int c0 = tid * 4;

  const vf4 sA0 = *(const vf4*)(sfin + 0 * B + c0);
  const vf4 sA1 = *(const vf4*)(sfin + 1 * B + c0);
  const vf4 sA2 = *(const vf4*)(sfin + 2 * B + c0);
  const vf4 sA3 = *(const vf4*)(sfin + 3 * B + c0);
  const vf4 xa  = *(const vf4*)(x + c0);
  const vf4 sB0 = *(const vf4*)(sfin + 0 * B + c0 + 1024);
  const vf4 sB1 = *(const vf4*)(sfin + 1 * B + c0 + 1024);
  const vf4 sB2 = *(const vf4*)(sfin + 2 * B + c0 + 1024);
  const vf4 sB3 = *(const vf4*)(sfin + 3 * B + c0 + 1024);
  const vf4 xb  = *(const vf4*)(x + c0 + 1024);

  float* op = hnew + (size_t)row0 * B + c0;
#pragma unroll
  for (int i = 0; i < RPB3; ++i) {
    const int n = row0 + i;
    const vf4 uv = *(const vf4*)(u + (size_t)n * RANK);
    const float mv = m[n];
    vf4 oA, oB;
    oA.x = fmaf(mv, xa.x,
                (sA0.x * uv.x + sA1.x * uv.y + sA2.x * uv.z + sA3.x * uv.w) * INV_N);
    oA.y = fmaf(mv, xa.y,
                (sA0.y * uv.x + sA1.y * uv.y + sA2.y * uv.z + sA3.y * uv.w) * INV_N);
    oA.z = fmaf(mv, xa.z,
                (sA0.z * uv.x + sA1.z * uv.y + sA2.z * uv.z + sA3.z * uv.w) * INV_N);
    oA.w = fmaf(mv, xa.w,
                (sA0.w * uv.x + sA1.w * uv.y + sA2.w * uv.z + sA3.w * uv.w) * INV_N);
    oB.x = fmaf(mv, xb.x,
                (sB0.x * uv.x + sB1.x * uv.y + sB2.x * uv.z + sB3.x * uv.w) * INV_N);
    oB.y = fmaf(mv, xb.y,
                (sB0.y * uv.x + sB1.y * uv.y + sB2.y * uv.z + sB3.y * uv.w) * INV_N);
    oB.z = fmaf(mv, xb.z,
                (sB0.z * uv.x + sB1.z * uv.y + sB2.z * uv.z + sB3.z * uv.w) * INV_N);
    oB.w = fmaf(mv, xb.w,
                (sB0.w * uv.x + sB1.w * uv.y + sB2.w * uv.z + sB3.w * uv.w) * INV_N);
    __builtin_nontemporal_store(oA, (vf4*)(op + (size_t)i * B));
    __builtin_nontemporal_store(oB, (vf4*)(op + (size_t)i * B + 1024));
  }
}

// ---------------------------------------------------------------------------
extern "C" void kernel_launch(void* const* d_in, const int* in_sizes, int n_in,
                              void* d_out, int out_size, void* d_ws,
                              size_t ws_size, hipStream_t stream) {
  const float* x = (const float*)d_in[0];  // [1, B]
  const float* h = (const float*)d_in[1];  // [N, B]
  const float* m = (const float*)d_in[2];  // [N, 1]
  const float* u = (const float*)d_in[3];  // [N, RANK]
  const float* v = (const float*)d_in[4];  // [N, RANK]
  const float* z = (const float*)d_in[5];  // [N, 1]

  float* y = (float*)d_out;            // output 0: y [1, B]
  float* hnew = (float*)d_out + B;     // output 1: h_new [N, B]

  unsigned short* partials = (unsigned short*)d_ws;       // [SPLITS][5][B] bf16, 10.5 MB
  float* sfin = (float*)(partials + (size_t)SPLITS * P);  // [RANK][B] fp32, 32 KB

  k_reduce_partial<<<SPLITS, 512, 0, stream>>>(h, v, z, partials);
  k_reduce_final<<<P / STRIPE, 512, 0, stream>>>(partials, sfin, y);
  k_update<<<N / RPB3, 256, 0, stream>>>(sfin, u, m, x, hnew);
}